// Round 9
// baseline (85.578 us; speedup 1.0000x reference)
//
#include <hip/hip_runtime.h>
#include <hip/hip_bf16.h>

// GAT fused kernel for MI355X (gfx950).  B=32, N=1024, F_IN=F_OUT=64, ALPHA=0.2
//
// Round 9: INSTRUMENTED PROBE of the r8 structure. Ledger: attn ~43-55us
// invariant across adjacency format/pattern, occupancy, ILP style; r5 probe
// showed all pipes <25% busy and flat per-rep time with L3-warm reps. This
// round REPs the r8 attn x3 in ONE dispatch (~165us -> top of rocprof with
// full counters; reps 0-1 sink to dummy ws). Body byte-identical to r8.
// Decision rules (pre-committed):
//   FETCH ~390MB -> HBM read path slow -> global_load_lds / wider loads next;
//   flat time + FETCH ~130-250MB -> internal stall -> LDS/shfl/sched next;
//   dispatch ~70-90us -> cold-fetch bound -> bitmask + register masks next.

#define B_  32
#define N_  1024
#define F_  64
#define REP 3

typedef __attribute__((ext_vector_type(8))) short  short8;
typedef __attribute__((ext_vector_type(4))) short  short4v;
typedef __attribute__((ext_vector_type(4))) float  floatx4;

__device__ __forceinline__ short f2bf(float x) {
    unsigned u = __float_as_uint(x);
    u += 0x7fff + ((u >> 16) & 1);   // RNE
    return (short)(u >> 16);
}

// ---------------- Kernel 1: prep ----------------
__global__ __launch_bounds__(256) void gat_prep(
    const float* __restrict__ nf, const float* __restrict__ W, const float* __restrict__ a,
    float* __restrict__ f1, float* __restrict__ f2, short* __restrict__ h_swz)
{
    const int wave = threadIdx.x >> 6;
    const int lane = threadIdx.x & 63;
    const long long row0 = (long long)blockIdx.x * 16 + wave * 4;

    const float* nf0 = nf + row0 * F_;
    float acc0 = 0.f, acc1 = 0.f, acc2 = 0.f, acc3 = 0.f;
    #pragma unroll 8
    for (int k = 0; k < F_; ++k) {
        float wk = W[k * F_ + lane];
        acc0 = fmaf(nf0[k],          wk, acc0);
        acc1 = fmaf(nf0[F_ + k],     wk, acc1);
        acc2 = fmaf(nf0[2 * F_ + k], wk, acc2);
        acc3 = fmaf(nf0[3 * F_ + k], wk, acc3);
    }
    const float a1 = a[lane], a2 = a[F_ + lane];

    float accs[4] = {acc0, acc1, acc2, acc3};
    #pragma unroll
    for (int r = 0; r < 4; ++r) {
        float v  = accs[r];
        float s1 = v * a1, s2 = v * a2;
        #pragma unroll
        for (int off = 32; off >= 1; off >>= 1) {
            s1 += __shfl_xor(s1, off, 64);
            s2 += __shfl_xor(s2, off, 64);
        }
        long long row = row0 + r;
        if (lane == 0) { f1[row] = s1; f2[row] = s2; }
        // swizzled bf16 store: B-frag layout for mfma_f32_16x16x32_bf16.
        int jl = (int)(row & (N_ - 1));
        int k  = jl & 31;
        int n  = lane & 15, fg = lane >> 4;
        int lp = n | ((k >> 3) << 4), e = k & 7;
        long long gc = row >> 5;   // global 32-row chunk id
        h_swz[(gc * 4 + fg) * 512 + lp * 8 + e] = f2bf(v);
    }
}

// ---------------- Kernel 2: fused attention (LDS-staged P, REP-probed) ----------------
// grid = B * (N/16) blocks, 256 threads = 4 waves.
__global__ __launch_bounds__(256, 4) void gat_attn(
    const int* __restrict__ adj, const float* __restrict__ f1g,
    const float* __restrict__ f2g, const short* __restrict__ h_swz,
    float* __restrict__ outp, float* __restrict__ dummy)
{
    __shared__ short Plds[4][16][256];     // per-wave P tile, XOR-swizzled, 32KB
    __shared__ float part[4][64][17];      // cross-wave numerator merge
    __shared__ float srow[4][16];          // cross-wave denominator merge

    const int wave = threadIdx.x >> 6;
    const int lane = threadIdx.x & 63;
    const int b  = blockIdx.x >> 6;        // 64 i-groups per batch
    const int ig = blockIdx.x & 63;
    const int i_base = ig * 16;
    const int iw = lane & 15;              // A-frag row within 16
    const int kg = lane >> 4;              // A-frag k-group (8 k's each)
    const int j0 = wave * 256;             // this wave's j-range

    const float f1v = f1g[b * N_ + i_base + iw];                 // lane&15 -> row
    const floatx4 f2v = *(const floatx4*)(f2g + b * N_ + j0 + lane * 4);
    const int* adjbase = adj + ((long long)b * N_ + i_base) * N_ + j0 + lane * 4;
    const short* hb = h_swz + (long long)b * 65536 + wave * 16384 + lane * 8;

    for (int rep = 0; rep < REP; ++rep) {
        // ---------- phase 1: contiguous adjacency streaming, P -> LDS ----------
        #pragma unroll
        for (int r = 0; r < 16; ++r) {
            int4 av = *(const int4*)(adjbase + (long long)r * N_);   // 16 indep rows
            float f1r = __shfl(f1v, r, 64);
            int am[4] = {av.x, av.y, av.z, av.w};
            short4v pk;
            #pragma unroll
            for (int e = 0; e < 4; ++e) {
                float x  = f1r + f2v[e];
                x        = fmaxf(x, 0.2f * x);              // leaky relu
                float pe = am[e] ? __expf(x) : 0.f;         // masked exp
                pk[e]    = f2bf(pe);
            }
            // XOR-swizzled store: logical granule g=lane>>1 -> physical g^(r&7)
            int g = (lane >> 1) ^ (r & 7);
            *(short4v*)&Plds[wave][r][g * 8 + (lane & 1) * 4] = pk;
        }

        // ---------- phase 2: A-frag ds_read + coalesced h + MFMA ----------
        floatx4 acc0 = {0.f,0.f,0.f,0.f}, acc1 = {0.f,0.f,0.f,0.f};
        floatx4 acc2 = {0.f,0.f,0.f,0.f}, acc3 = {0.f,0.f,0.f,0.f};
        floatx4 acc4 = {0.f,0.f,0.f,0.f};                    // denominator (B=ones)
        short8 ones;
        #pragma unroll
        for (int e = 0; e < 8; ++e) ones[e] = (short)0x3F80; // bf16 1.0

        #pragma unroll
        for (int jc = 0; jc < 8; ++jc) {
            // logical granule g = jc*4+kg, physical g^(iw&7)
            int g = (jc * 4 + kg) ^ (iw & 7);
            short8 af = *(const short8*)&Plds[wave][iw][g * 8];

            const short* hc = hb + jc * 2048;
            short8 b0 = *(const short8*)(hc);
            short8 b1 = *(const short8*)(hc + 512);
            short8 b2 = *(const short8*)(hc + 1024);
            short8 b3 = *(const short8*)(hc + 1536);

            acc0 = __builtin_amdgcn_mfma_f32_16x16x32_bf16(af, b0, acc0, 0, 0, 0);
            acc1 = __builtin_amdgcn_mfma_f32_16x16x32_bf16(af, b1, acc1, 0, 0, 0);
            acc2 = __builtin_amdgcn_mfma_f32_16x16x32_bf16(af, b2, acc2, 0, 0, 0);
            acc3 = __builtin_amdgcn_mfma_f32_16x16x32_bf16(af, b3, acc3, 0, 0, 0);
            acc4 = __builtin_amdgcn_mfma_f32_16x16x32_bf16(af, ones, acc4, 0, 0, 0);
        }

        // denominator rows: acc4 reg r at lane (iw,kg) = rowsum(kg*4+r)
        if (iw == 0) {
            #pragma unroll
            for (int r = 0; r < 4; ++r) srow[wave][kg * 4 + r] = acc4[r];
        }

        floatx4 accs[4] = {acc0, acc1, acc2, acc3};
        #pragma unroll
        for (int fg = 0; fg < 4; ++fg)
            #pragma unroll
            for (int r = 0; r < 4; ++r)
                part[wave][lane][fg * 4 + r] = accs[fg][r];
        __syncthreads();

        // rep<REP-1 -> dead ws sink (keeps body live, rule #17); last -> out
        float* obase = (rep == REP - 1) ? outp : dummy;
        const int fg = wave;
        float* orow = obase + ((long long)b * N_ + i_base) * F_;
        #pragma unroll
        for (int r = 0; r < 4; ++r) {
            const int idx  = fg * 4 + r;
            const int rloc = kg * 4 + r;
            float tot  = part[0][lane][idx] + part[1][lane][idx]
                       + part[2][lane][idx] + part[3][lane][idx];
            float sden = srow[0][rloc] + srow[1][rloc] + srow[2][rloc] + srow[3][rloc];
            float v = tot / sden;
            v = v > 0.f ? v : (__expf(v) - 1.f);    // ELU (alpha=1)
            orow[(long long)rloc * F_ + fg * 16 + iw] = v;
        }
        __syncthreads();   // part[]/srow[]/Plds reused next rep
    }
}

extern "C" void kernel_launch(void* const* d_in, const int* in_sizes, int n_in,
                              void* d_out, int out_size, void* d_ws, size_t ws_size,
                              hipStream_t stream) {
    const float* nf  = (const float*)d_in[0];
    const int*   adj = (const int*)d_in[1];     // bool -> int32 per harness
    const float* W   = (const float*)d_in[2];
    const float* a   = (const float*)d_in[3];
    float* out = (float*)d_out;

    char* ws = (char*)d_ws;
    float* f1    = (float*)ws;                    // 128KB
    float* f2    = (float*)(ws + 131072);         // 128KB
    short* h_swz = (short*)(ws + 262144);         // 4MB
    float* dummy = (float*)(ws + 262144 + 4194304); // 8MB dead probe sink

    hipLaunchKernelGGL(gat_prep, dim3(B_ * N_ / 16), dim3(256), 0, stream,
                       nf, W, a, f1, f2, h_swz);
    hipLaunchKernelGGL(gat_attn, dim3(B_ * (N_ / 16)), dim3(256), 0, stream,
                       adj, f1, f2, h_swz, out, dummy);
}